// Round 6
// baseline (238.200 us; speedup 1.0000x reference)
//
#include <hip/hip_runtime.h>
#include <math.h>

#define C_HUB 1.345f

// ---------------- DPP helpers (VALU-pipe cross-lane) ----
template<int CTRL, bool BC>
__device__ __forceinline__ float fdpp(float old_, float src) {
    return __int_as_float(__builtin_amdgcn_update_dpp(
        __float_as_int(old_), __float_as_int(src), CTRL, 0xf, 0xf, BC));
}
// wave64 sum; result valid at lane 63 only
__device__ __forceinline__ float wsum63(float v) {
    v += fdpp<0x111, true>(0.f, v);   // row_shr:1
    v += fdpp<0x112, true>(0.f, v);   // row_shr:2
    v += fdpp<0x114, true>(0.f, v);   // row_shr:4
    v += fdpp<0x118, true>(0.f, v);   // row_shr:8
    v += fdpp<0x142, true>(0.f, v);   // row_bcast:15
    v += fdpp<0x143, true>(0.f, v);   // row_bcast:31
    return v;
}
template<int CTRL>
__device__ __forceinline__ unsigned udpp_keep(unsigned v) {
    return (unsigned)__builtin_amdgcn_update_dpp((int)v, (int)v, CTRL, 0xf, 0xf, false);
}
// wave64 unsigned min; valid at lane 63
__device__ __forceinline__ unsigned wmin63(unsigned v) {
    v = min(v, udpp_keep<0x111>(v));
    v = min(v, udpp_keep<0x112>(v));
    v = min(v, udpp_keep<0x114>(v));
    v = min(v, udpp_keep<0x118>(v));
    v = min(v, udpp_keep<0x142>(v));
    v = min(v, udpp_keep<0x143>(v));
    return v;
}
__device__ __forceinline__ float bcast63(float v) {
    return __int_as_float(__builtin_amdgcn_readlane(__float_as_int(v), 63));
}

// monotone f32 <-> u32 key maps
__device__ __forceinline__ unsigned f2k(float f) {
    unsigned b = __float_as_uint(f);
    return (b & 0x80000000u) ? ~b : (b | 0x80000000u);
}
__device__ __forceinline__ float k2f(unsigned k) {
    return __uint_as_float((k & 0x80000000u) ? (k ^ 0x80000000u) : ~k);
}

// n-th smallest (1-indexed) of 1024 keys (16/lane), wave-synchronous
__device__ __forceinline__ unsigned wave_sel(const unsigned k[16], int n) {
    unsigned hi = 0u;
    for (int b = 31; b >= 0; --b) {
        unsigned pat = hi >> b;
        int cnt = 0;
        #pragma unroll
        for (int v = 0; v < 16; ++v)
            cnt += __popcll(__ballot((k[v] >> b) == pat));
        if (n > cnt) { hi |= (1u << b); n -= cnt; }
    }
    return hi;
}
// exact median (mean of middle two) of the 1024 keys
__device__ __forceinline__ float wave_median(const unsigned k[16]) {
    unsigned k1 = wave_sel(k, 512);
    int cle = 0;
    #pragma unroll
    for (int v = 0; v < 16; ++v) cle += __popcll(__ballot(k[v] <= k1));
    unsigned k2 = k1;
    if (cle < 513) {
        unsigned mg = 0xFFFFFFFFu;
        #pragma unroll
        for (int v = 0; v < 16; ++v) if (k[v] > k1) mg = min(mg, k[v]);
        mg = wmin63(mg);
        k2 = (unsigned)__builtin_amdgcn_readlane((int)mg, 63);
    }
    return 0.5f * (k2f(k1) + k2f(k2));
}

// ---------------------------------------------------------------------------
// Fused transpose: X (1024x1024)->XT plus U (1024x32)->UT (blocks with by==32)
// ---------------------------------------------------------------------------
__global__ void transpose_kernel(const float* __restrict__ X, float* __restrict__ XT,
                                 const float* __restrict__ U, float* __restrict__ UT) {
    if (blockIdx.y == 32) {
        int id = blockIdx.x * 256 + threadIdx.y * 32 + threadIdx.x;  // 0..8191
        #pragma unroll
        for (int s = 0; s < 4; ++s) {
            int e = id + s * 8192;
            int c = e >> 10, m = e & 1023;
            UT[e] = U[m * 32 + c];
        }
        return;
    }
    __shared__ float tile[32][33];
    int bx = blockIdx.x, by = blockIdx.y;
    int x = bx * 32 + threadIdx.x;
    int ybase = by * 32;
    for (int dy = threadIdx.y; dy < 32; dy += 8)
        tile[dy][threadIdx.x] = X[(ybase + dy) * 1024 + x];
    __syncthreads();
    int xo = by * 32 + threadIdx.x;
    int yob = bx * 32;
    for (int dy = threadIdx.y; dy < 32; dy += 8)
        XT[(yob + dy) * 1024 + xo] = tile[threadIdx.x][dy];
}

// ---------------------------------------------------------------------------
// Partial Gram: block b computes AT[:,128b:128b+128] * (same)^T into Gpart[b]
// ---------------------------------------------------------------------------
__global__ __launch_bounds__(256) void gram_kernel(const float* __restrict__ AT,
                                                   float* __restrict__ Gpart) {
    __shared__ float s[32][129];
    const int b = blockIdx.x, tid = threadIdx.x;
    const int k0 = b << 7;
    for (int i = tid; i < 4096; i += 256) {
        int r = i >> 7, c = i & 127;
        s[r][c] = AT[(r << 10) + k0 + c];
    }
    __syncthreads();
    const int c2 = tid & 31, c1b = tid >> 5;
    float acc[4] = {0.f, 0.f, 0.f, 0.f};
    for (int k = 0; k < 128; ++k) {
        float bv = s[c2][k];
        #pragma unroll
        for (int i = 0; i < 4; ++i)
            acc[i] += s[c1b + (i << 3)][k] * bv;
    }
    #pragma unroll
    for (int i = 0; i < 4; ++i)
        Gpart[(b << 10) + ((c1b + (i << 3)) << 5) + c2] = acc[i];
}

// ---------------------------------------------------------------------------
// Sum partials, invert 32x32 SPD Gram via f32 Gauss-Jordan on one wave.
// ---------------------------------------------------------------------------
__global__ __launch_bounds__(64) void inv_kernel(const float* __restrict__ Gpart,
                                                 float* __restrict__ Ginv) {
    const int lane = threadIdx.x;
    float col[32];
    if (lane < 32) {
        #pragma unroll
        for (int r = 0; r < 32; ++r) {
            float a = 0.f;
            #pragma unroll
            for (int b = 0; b < 8; ++b) a += Gpart[(b << 10) + (r << 5) + lane];
            col[r] = a;
        }
    } else {
        #pragma unroll
        for (int r = 0; r < 32; ++r) col[r] = (lane - 32 == r) ? 1.f : 0.f;
    }
    #pragma unroll
    for (int k = 0; k < 32; ++k) {
        float piv = __shfl(col[k], k, 64);
        float pr = 1.0f / piv;
        col[k] *= pr;
        #pragma unroll
        for (int r = 0; r < 32; ++r) {
            if (r == k) continue;
            float f = __shfl(col[r], k, 64);
            col[r] -= f * col[k];
        }
    }
    if (lane >= 32) {
        #pragma unroll
        for (int r = 0; r < 32; ++r)
            Ginv[(r << 5) + (lane - 32)] = col[r];
    }
}

// ---------------------------------------------------------------------------
// IRLS: 2 tasks per block (tasks j = 2*blockIdx.x + t), 256 threads, 512 blocks.
// Thread i owns elements 4i..4i+3. Wave t (t<2) owns task t's medians.
// z[q] = A * shifted-rp; Ginv (symmetric) folded into the beta update.
// R5 lesson: full unroll of the const-trip memory loops made LLVM hoist
// 16-32 float4 loads -> >128 VGPR pressure -> 26 MB scratch spill traffic.
// unroll 8 (matvec) / unroll 2 (z kk-loop) cap in-flight loads; Y re-read
// from global (block-private row, L1-resident) instead of 8 persistent VGPRs.
// ---------------------------------------------------------------------------
__global__ __launch_bounds__(256, 2) void irls_kernel(
    const float* __restrict__ Yr, const float* __restrict__ A32,
    const float* __restrict__ Ginv, const float* __restrict__ kb,
    const float* __restrict__ bsrc, float* __restrict__ vnew,
    float* __restrict__ out, int phase)
{
    const int b2 = blockIdx.x;
    const int tid = threadIdx.x;
    const int lane = tid & 63, wv_id = tid >> 6;

    __shared__ __align__(16) float s_rp[2][1024];
    __shared__ __align__(16) float s_beta[32][2];     // [c][t]
    __shared__ float s_g[32][35];                     // s_g[e][1+c] = Ginv[e][c]; cols 0,33 zero
    __shared__ float s_z[2][3][32];                   // [t][q][e]
    __shared__ float s_kern[2][9];
    __shared__ float s_part[4][2];                    // [wave][t]
    __shared__ float s_scale[2];

    const float4* Y4 = (const float4*)Yr;
    const float4* A4 = (const float4*)A32;

    // stage Ginv with zero guard columns (symmetric: [e][1+c] indexing == G[c][e])
    for (int i = tid; i < 1024; i += 256) {
        int e = i >> 5, c = i & 31;
        s_g[e][1 + c] = Ginv[i];
    }
    if (tid < 32) s_g[tid][0] = 0.f;
    else if (tid < 64) s_g[tid - 32][33] = 0.f;
    if (tid >= 64 && tid < 128) {
        int e = tid - 64, t = e >> 5, c = e & 31, j = (b2 << 1) + t;
        s_beta[c][t] = (phase == 0) ? bsrc[(c << 10) + j] : bsrc[j * 32 + c];
    }
    if (tid >= 192 && tid < 210) {
        int e = tid - 192, t = e / 9, r = e % 9, j = (b2 << 1) + t;
        s_kern[t][r] = (phase == 0) ? kb[j * 9 + r] : kb[j * 9 + (r % 3) * 3 + (r / 3)];
    }
    __syncthreads();                                     // B1

    // ---- matvec: r[t] = y[t] - A-rows dot beta[t]; y re-read (L1-hot) ----
    auto matvec = [&](float4* r) {
        r[0] = Y4[(((b2 << 1) + 0) << 8) + tid];
        r[1] = Y4[(((b2 << 1) + 1) << 8) + tid];
        #pragma unroll 8
        for (int c = 0; c < 32; ++c) {
            float2 bb = *((const float2*)s_beta[c]);
            float4 a = A4[(c << 8) + tid];
            r[0].x -= a.x * bb.x; r[0].y -= a.y * bb.x; r[0].z -= a.z * bb.x; r[0].w -= a.w * bb.x;
            r[1].x -= a.x * bb.y; r[1].y -= a.y * bb.y; r[1].z -= a.z * bb.y; r[1].w -= a.w * bb.y;
        }
    };

    float4 r[2];
    matvec(r);
    #pragma unroll
    for (int t = 0; t < 2; ++t) ((float4*)s_rp[t])[tid] = r[t];
    __syncthreads();                                     // B2

    // ---- per-wave exact medians -> initial scale (waves 0,1 only) ----
    if (wv_id < 2) {
        float fv[16]; unsigned kk[16];
        #pragma unroll
        for (int v = 0; v < 16; ++v) fv[v] = s_rp[wv_id][lane + (v << 6)];
        #pragma unroll
        for (int v = 0; v < 16; ++v) kk[v] = f2k(fv[v]);
        float med = wave_median(kk);
        #pragma unroll
        for (int v = 0; v < 16; ++v) kk[v] = f2k(fabsf(fv[v] - med));
        float mad = wave_median(kk);
        if (lane == 0) s_scale[wv_id] = 1.4815f * mad;
    }
    __syncthreads();                                     // B3

    float scale[2];
    #pragma unroll
    for (int t = 0; t < 2; ++t) scale[t] = s_scale[t];

    const float inv_denom = 1.0f / (2.0f * 0.7102f * (1024.0f - 32.0f - 1.0f));
    const float C2 = C_HUB * C_HUB;

    for (int it = 0; it < 3; ++it) {
        matvec(r);

        // r_chi = 0.5*min(u^2, C^2); block sum per task
        #pragma unroll
        for (int t = 0; t < 2; ++t) {
            float s = scale[t];
            float u0 = r[t].x / s, u1 = r[t].y / s, u2 = r[t].z / s, u3 = r[t].w / s;
            float part = 0.5f * (fminf(u0 * u0, C2) + fminf(u1 * u1, C2) +
                                 fminf(u2 * u2, C2) + fminf(u3 * u3, C2));
            float ps = wsum63(part);
            if (lane == 63) s_part[wv_id][t] = ps;
        }
        __syncthreads();                                 // B4

        // scale update + r_pseu -> LDS
        #pragma unroll
        for (int t = 0; t < 2; ++t) {
            float ss = s_part[0][t] + s_part[1][t] + s_part[2][t] + s_part[3][t];
            float s = sqrtf(2.0f * scale[t] * scale[t] * inv_denom * ss);
            scale[t] = s;
            float4 rp;
            rp.x = fminf(fmaxf(r[t].x / s, -C_HUB), C_HUB) * s;
            rp.y = fminf(fmaxf(r[t].y / s, -C_HUB), C_HUB) * s;
            rp.z = fminf(fmaxf(r[t].z / s, -C_HUB), C_HUB) * s;
            rp.w = fminf(fmaxf(r[t].w / s, -C_HUB), C_HUB) * s;
            ((float4*)s_rp[t])[tid] = rp;
        }
        __syncthreads();                                 // B5

        // ---- z[q][e] = sum_j A32[e][j] * rp[j+1-q] (shifts applied to A) ----
        #pragma unroll 1
        for (int half = 0; half < 2; ++half) {
            float a0[4][2], a1[4][2], a2[4][2];
            #pragma unroll
            for (int cc = 0; cc < 4; ++cc)
                #pragma unroll
                for (int t = 0; t < 2; ++t) { a0[cc][t] = 0.f; a1[cc][t] = 0.f; a2[cc][t] = 0.f; }
            float wlast[4] = {0.f, 0.f, 0.f, 0.f};
            float rplast[2] = {0.f, 0.f};
            #pragma unroll 2
            for (int kk = 0; kk < 4; ++kk) {
                float4 rp4[2]; float rpl_new[2];
                #pragma unroll
                for (int t = 0; t < 2; ++t) {
                    rp4[t] = ((const float4*)s_rp[t])[(kk << 6) + lane];
                    rpl_new[t] = bcast63(rp4[t].w);
                }
                #pragma unroll
                for (int cc = 0; cc < 4; ++cc) {
                    const int cp = (wv_id << 3) + (half << 2) + cc;
                    float4 w4 = A4[(cp << 8) + (kk << 6) + lane];
                    float wprev = __shfl_up(w4.w, 1, 64);
                    if (lane == 0) wprev = wlast[cc];
                    float wnext = __shfl_down(w4.x, 1, 64);
                    if (lane == 63) wnext = 0.f;
                    float wcomp = (lane == 0) ? w4.x : 0.f;   // deferred chunk-edge term
                    #pragma unroll
                    for (int t = 0; t < 2; ++t) {
                        float4 rp = rp4[t];
                        a1[cc][t] += w4.x * rp.x + w4.y * rp.y + w4.z * rp.z + w4.w * rp.w;
                        a0[cc][t] += wprev * rp.x + w4.x * rp.y + w4.y * rp.z + w4.z * rp.w;
                        a2[cc][t] += w4.y * rp.x + w4.z * rp.y + w4.w * rp.z + wnext * rp.w
                                   + wcomp * rplast[t];
                    }
                    wlast[cc] = bcast63(w4.w);
                }
                #pragma unroll
                for (int t = 0; t < 2; ++t) rplast[t] = rpl_new[t];
            }
            #pragma unroll
            for (int cc = 0; cc < 4; ++cc) {
                const int cp = (wv_id << 3) + (half << 2) + cc;
                #pragma unroll
                for (int t = 0; t < 2; ++t) {
                    float z0 = wsum63(a0[cc][t]);
                    float z1 = wsum63(a1[cc][t]);
                    float z2 = wsum63(a2[cc][t]);
                    if (lane == 63) {
                        s_z[t][0][cp] = z0; s_z[t][1][cp] = z1; s_z[t][2][cp] = z2;
                    }
                }
            }
        }
        __syncthreads();                                 // B6

        // ---- beta[c][t] += sum_e sum_q (sum_p kern[p][q] G[c+p-1][e]) z[q][e]
        //      G[x][e] read via symmetry as s_g[e][1+x]; guard cols handle x=-1,32.
        if (tid < 64) {
            int t = tid >> 5, c = tid & 31;
            float kn[9];
            #pragma unroll
            for (int x = 0; x < 9; ++x) kn[x] = s_kern[t][x];
            float d = 0.f;
            #pragma unroll 4
            for (int e = 0; e < 32; ++e) {
                float gm = s_g[e][c];       // G[c-1][e]
                float gc = s_g[e][c + 1];   // G[c  ][e]
                float gp = s_g[e][c + 2];   // G[c+1][e]
                float z0 = s_z[t][0][e], z1 = s_z[t][1][e], z2 = s_z[t][2][e];
                d += (kn[0] * gm + kn[3] * gc + kn[6] * gp) * z0
                   + (kn[1] * gm + kn[4] * gc + kn[7] * gp) * z1
                   + (kn[2] * gm + kn[5] * gc + kn[8] * gp) * z2;
            }
            s_beta[c][t] += d;
        }
        __syncthreads();                                 // B7
    }

    if (tid < 64) {
        int t = tid >> 5, c = tid & 31, j = (b2 << 1) + t;
        float bv = s_beta[c][t];
        if (phase == 0) {
            vnew[(c << 10) + j] = bv;
            out[c * 2048 + 1024 + j] = bv;
        } else {
            out[c * 2048 + j] = bv;
        }
    }
}

// ---------------------------------------------------------------------------
extern "C" void kernel_launch(void* const* d_in, const int* in_sizes, int n_in,
                              void* d_out, int out_size, void* d_ws, size_t ws_size,
                              hipStream_t stream) {
    const float* X  = (const float*)d_in[0];
    const float* U  = (const float*)d_in[1];
    const float* V  = (const float*)d_in[2];
    const float* CK = (const float*)d_in[3];
    float* out = (float*)d_out;

    float* f     = (float*)d_ws;
    float* XT    = f;                    // 1024*1024
    float* UT    = f + (1 << 20);        // 32*1024
    float* Vn    = UT + 32768;           // 32*1024
    float* Gpart = Vn + 32768;           // 8*1024
    float* Ginv  = Gpart + 8192;         // 1024

    transpose_kernel<<<dim3(32, 33), dim3(32, 8), 0, stream>>>(X, XT, U, UT);

    gram_kernel<<<8, 256, 0, stream>>>(UT, Gpart);
    inv_kernel<<<1, 64, 0, stream>>>(Gpart, Ginv);
    irls_kernel<<<512, 256, 0, stream>>>(XT, UT, Ginv, CK, V, Vn, out, 0);

    gram_kernel<<<8, 256, 0, stream>>>(Vn, Gpart);
    inv_kernel<<<1, 64, 0, stream>>>(Gpart, Ginv);
    irls_kernel<<<512, 256, 0, stream>>>(X, Vn, Ginv, CK + 1023 * 9, U, nullptr, out, 1);
}